// Round 3
// baseline (356.488 us; speedup 1.0000x reference)
//
#include <hip/hip_runtime.h>

#define NFEAT 128
#define NHID  64
#define NOUT  21

typedef unsigned int uint;

// bf16 pack/unpack (RTN-even)
__device__ inline uint packbf2(float a, float b) {
    uint ua = __float_as_uint(a), ub = __float_as_uint(b);
    ua = (ua + 0x7FFFu + ((ua >> 16) & 1u)) >> 16;
    ub = (ub + 0x7FFFu + ((ub >> 16) & 1u)) >> 16;
    return ua | (ub << 16);
}
__device__ inline float bflo(uint v) { return __uint_as_float(v << 16); }
__device__ inline float bfhi(uint v) { return __uint_as_float(v & 0xffff0000u); }

// ================= CSR build (counting sort by dst) =================

__global__ __launch_bounds__(256) void k_count(const int* __restrict__ dst, int* cnt, int E) {
    int e = blockIdx.x * 256 + threadIdx.x;
    if (e < E) atomicAdd(&cnt[dst[e]], 1);
}

// block-local exclusive scan (1024 elems/block) + dinv = rsqrt(deg+1)
__global__ __launch_bounds__(256) void k_scan1(const int* __restrict__ cnt, int* __restrict__ rowptr,
                                               int* __restrict__ bsum, float* __restrict__ dinv, int N) {
    __shared__ int sh[256];
    int tid = threadIdx.x;
    int base = blockIdx.x * 1024 + tid * 4;
    int v[4]; int s = 0;
#pragma unroll
    for (int j = 0; j < 4; ++j) {
        v[j] = (base + j < N) ? cnt[base + j] : 0;
        if (base + j < N) dinv[base + j] = rsqrtf((float)(v[j] + 1));
        s += v[j];
    }
    sh[tid] = s; __syncthreads();
    for (int off = 1; off < 256; off <<= 1) {
        int t = (tid >= off) ? sh[tid - off] : 0;
        __syncthreads();
        sh[tid] += t;
        __syncthreads();
    }
    int run = sh[tid] - s;
#pragma unroll
    for (int j = 0; j < 4; ++j) { if (base + j < N) rowptr[base + j] = run; run += v[j]; }
    if (tid == 255) bsum[blockIdx.x] = sh[255];
}

__global__ __launch_bounds__(128) void k_scan2(int* bsum, int nb) {
    __shared__ int sh[128];
    int tid = threadIdx.x;
    int v = (tid < nb) ? bsum[tid] : 0;
    sh[tid] = v; __syncthreads();
    for (int off = 1; off < 128; off <<= 1) {
        int t = (tid >= off) ? sh[tid - off] : 0;
        __syncthreads();
        sh[tid] += t;
        __syncthreads();
    }
    if (tid < nb) bsum[tid] = sh[tid] - v;
}

// finalize rowptr, copy to fill (scatter cursors), rowptr[N]=E
__global__ __launch_bounds__(256) void k_scan3(int* __restrict__ rowptr, int* __restrict__ fill,
                                               const int* __restrict__ bsum, int N, int E) {
    int tid = threadIdx.x;
    int base = blockIdx.x * 1024 + tid * 4;
    int add = bsum[blockIdx.x];
#pragma unroll
    for (int j = 0; j < 4; ++j)
        if (base + j < N) { int r = rowptr[base + j] + add; rowptr[base + j] = r; fill[base + j] = r; }
    if (blockIdx.x == 0 && tid == 0) rowptr[N] = E;
}

__global__ __launch_bounds__(256) void k_scatter(const int* __restrict__ src, const int* __restrict__ dst,
                                                 int* __restrict__ fill, int* __restrict__ esrc, int E) {
    int e = blockIdx.x * 256 + threadIdx.x;
    if (e >= E) return;
    int pos = atomicAdd(&fill[dst[e]], 1);
    esrc[pos] = src[e];
}

// ===== GEMM1: h' = dinv * (x @ W1), stored packed bf16 [N][32 uints] =====

__global__ __launch_bounds__(256) void k_gemm1(const float* __restrict__ x, const float* __restrict__ W1,
                                               const float* __restrict__ dinv, uint* __restrict__ hb, int N) {
    __shared__ float Ws[NFEAT * NHID];  // 32 KB
    int tid = threadIdx.x;
#pragma unroll
    for (int i = 0; i < 8; ++i) {
        int idx = (tid + i * 256) * 4;
        *(float4*)&Ws[idx] = *(const float4*)&W1[idx];
    }
    __syncthreads();
    int row = blockIdx.x * 64 + (tid >> 2);
    if (row >= N) return;
    int cg = (tid & 3) * 16;
    float acc[16];
#pragma unroll
    for (int j = 0; j < 16; ++j) acc[j] = 0.f;
    const float* xr = x + (size_t)row * NFEAT;
#pragma unroll 4
    for (int k4 = 0; k4 < NFEAT / 4; ++k4) {
        float4 xv = *(const float4*)&xr[k4 * 4];
        float xs[4] = {xv.x, xv.y, xv.z, xv.w};
#pragma unroll
        for (int kk = 0; kk < 4; ++kk) {
            const float* wrow = &Ws[(k4 * 4 + kk) * NHID + cg];
#pragma unroll
            for (int j4 = 0; j4 < 4; ++j4) {
                float4 w = *(const float4*)&wrow[j4 * 4];
                acc[j4 * 4 + 0] = fmaf(xs[kk], w.x, acc[j4 * 4 + 0]);
                acc[j4 * 4 + 1] = fmaf(xs[kk], w.y, acc[j4 * 4 + 1]);
                acc[j4 * 4 + 2] = fmaf(xs[kk], w.z, acc[j4 * 4 + 2]);
                acc[j4 * 4 + 3] = fmaf(xs[kk], w.w, acc[j4 * 4 + 3]);
            }
        }
    }
    float dv = dinv[row];
    uint up[8];
#pragma unroll
    for (int j = 0; j < 8; ++j) up[j] = packbf2(acc[2 * j] * dv, acc[2 * j + 1] * dv);
    uint* hr = hb + (size_t)row * 32 + (tid & 3) * 8;
    ((uint4*)hr)[0] = make_uint4(up[0], up[1], up[2], up[3]);
    ((uint4*)hr)[1] = make_uint4(up[4], up[5], up[6], up[7]);
}

// ===== agg1: o1[d] = relu(b1 + dv_d*(h'[d] + sum_e h'[src_e])), f32 out =====
// wave per node; lanes 0-31 even edges / 32-63 odd edges; lane owns 2 feats.

__global__ __launch_bounds__(256) void k_agg1(const int* __restrict__ rowptr, const int* __restrict__ esrc,
                                              const uint* __restrict__ hb, const float* __restrict__ dinv,
                                              const float* __restrict__ b1, float* __restrict__ o1, int N) {
    int tid = threadIdx.x;
    int node = blockIdx.x * 4 + (tid >> 6);
    if (node >= N) return;
    int lane = tid & 63;
    int half = lane >> 5;
    int c = lane & 31;
    uint sv = hb[(size_t)node * 32 + c];
    float ax = half ? 0.f : bflo(sv);
    float ay = half ? 0.f : bfhi(sv);
    int beg = rowptr[node], end = rowptr[node + 1];
    int i = beg + half;
    for (; i + 2 < end; i += 4) {
        int s0 = esrc[i], s1 = esrc[i + 2];
        uint v0 = hb[(size_t)s0 * 32 + c];
        uint v1 = hb[(size_t)s1 * 32 + c];
        ax += bflo(v0); ay += bfhi(v0);
        ax += bflo(v1); ay += bfhi(v1);
    }
    if (i < end) {
        uint v = hb[(size_t)esrc[i] * 32 + c];
        ax += bflo(v); ay += bfhi(v);
    }
    ax += __shfl_xor(ax, 32);
    ay += __shfl_xor(ay, 32);
    if (!half) {
        float dv = dinv[node];
        float2 bv = ((const float2*)b1)[c];
        float2 r;
        r.x = fmaxf(fmaf(ax, dv, bv.x), 0.f);
        r.y = fmaxf(fmaf(ay, dv, bv.y), 0.f);
        ((float2*)(o1 + (size_t)node * NHID))[c] = r;
    }
}

// ===== GEMM2: h2' = dinv * (o1 @ W2), packed bf16 padded to 24 feats [N][12 uints] =====

__global__ __launch_bounds__(128) void k_gemm2(const float* __restrict__ o1, const float* __restrict__ W2,
                                               const float* __restrict__ dinv, uint* __restrict__ h2b, int N) {
    __shared__ float rs[128 * 65];      // stride 65: conflict-free
    __shared__ float Ws[NHID * NOUT];
    int tid = threadIdx.x;
    for (int i = tid; i < NHID * NOUT; i += 128) Ws[i] = W2[i];
    int base = blockIdx.x * 128;
#pragma unroll
    for (int i = 0; i < 16; ++i) {
        int idx = tid + i * 128;
        int row = idx >> 4;
        int f4 = (idx & 15) * 4;
        int grow = base + row;
        float4 v = make_float4(0.f, 0.f, 0.f, 0.f);
        if (grow < N) v = *(const float4*)&o1[(size_t)grow * NHID + f4];
        float* d = &rs[row * 65 + f4];
        d[0] = v.x; d[1] = v.y; d[2] = v.z; d[3] = v.w;
    }
    __syncthreads();
    int row = base + tid;
    if (row >= N) return;
    float acc[NOUT];
#pragma unroll
    for (int j = 0; j < NOUT; ++j) acc[j] = 0.f;
    for (int k = 0; k < NHID; ++k) {
        float av = rs[tid * 65 + k];
#pragma unroll
        for (int j = 0; j < NOUT; ++j) acc[j] = fmaf(av, Ws[k * NOUT + j], acc[j]);
    }
    float dv = dinv[row];
    uint up[12];
#pragma unroll
    for (int j = 0; j < 10; ++j) up[j] = packbf2(acc[2 * j] * dv, acc[2 * j + 1] * dv);
    up[10] = packbf2(acc[20] * dv, 0.f);
    up[11] = 0u;
    uint* hr = h2b + (size_t)row * 12;
    ((uint4*)hr)[0] = make_uint4(up[0], up[1], up[2], up[3]);
    ((uint4*)hr)[1] = make_uint4(up[4], up[5], up[6], up[7]);
    ((uint4*)hr)[2] = make_uint4(up[8], up[9], up[10], up[11]);
}

// ===== agg2: out[d] = b2 + dv_d*(h2'[d] + sum_e h2'[src_e]) =====
// 4 lanes per node, lane q owns feats 6q..6q+5 (3 uints); row = 48 B = 1 line.

__global__ __launch_bounds__(256) void k_agg2(const int* __restrict__ rowptr, const int* __restrict__ esrc,
                                              const uint* __restrict__ h2b, const float* __restrict__ dinv,
                                              const float* __restrict__ b2, float* __restrict__ out, int N) {
    int tid = threadIdx.x;
    int node = blockIdx.x * 64 + (tid >> 2);
    if (node >= N) return;
    int q = tid & 3;
    const uint* sp = h2b + (size_t)node * 12 + q * 3;
    uint u0 = sp[0], u1 = sp[1], u2 = sp[2];
    float a0 = bflo(u0), a1 = bfhi(u0), a2 = bflo(u1), a3 = bfhi(u1), a4 = bflo(u2), a5 = bfhi(u2);
    int beg = rowptr[node], end = rowptr[node + 1];
    int i = beg;
    for (; i + 1 < end; i += 2) {
        const uint* p0 = h2b + (size_t)esrc[i] * 12 + q * 3;
        const uint* p1 = h2b + (size_t)esrc[i + 1] * 12 + q * 3;
        uint x0 = p0[0], x1 = p0[1], x2 = p0[2];
        uint y0 = p1[0], y1 = p1[1], y2 = p1[2];
        a0 += bflo(x0) + bflo(y0); a1 += bfhi(x0) + bfhi(y0);
        a2 += bflo(x1) + bflo(y1); a3 += bfhi(x1) + bfhi(y1);
        a4 += bflo(x2) + bflo(y2); a5 += bfhi(x2) + bfhi(y2);
    }
    if (i < end) {
        const uint* p0 = h2b + (size_t)esrc[i] * 12 + q * 3;
        uint x0 = p0[0], x1 = p0[1], x2 = p0[2];
        a0 += bflo(x0); a1 += bfhi(x0);
        a2 += bflo(x1); a3 += bfhi(x1);
        a4 += bflo(x2); a5 += bfhi(x2);
    }
    float dv = dinv[node];
    float* orow = out + (size_t)node * NOUT;
    int col = q * 6;
    float av[6] = {a0, a1, a2, a3, a4, a5};
#pragma unroll
    for (int j = 0; j < 6; ++j)
        if (col + j < NOUT) orow[col + j] = fmaf(dv, av[j], b2[col + j]);
}

// ================= launch =================

extern "C" void kernel_launch(void* const* d_in, const int* in_sizes, int n_in,
                              void* d_out, int out_size, void* d_ws, size_t ws_size,
                              hipStream_t stream) {
    const float* x  = (const float*)d_in[0];
    const int*   ei = (const int*)d_in[1];
    const float* W1 = (const float*)d_in[2];
    const float* b1 = (const float*)d_in[3];
    const float* W2 = (const float*)d_in[4];
    const float* b2 = (const float*)d_in[5];
    float* out = (float*)d_out;

    int N = in_sizes[0] / NFEAT;
    int E = in_sizes[1] / 2;
    const int* src = ei;
    const int* dst = ei + E;

    char* p = (char*)d_ws;
    auto alloc = [&](size_t bytes) { void* r = (void*)p; p += (bytes + 255) & ~(size_t)255; return r; };
    int*   cnt    = (int*)alloc((size_t)N * 4);
    int*   rowptr = (int*)alloc((size_t)(N + 1) * 4);
    int*   fill   = (int*)alloc((size_t)N * 4);
    int*   bsum   = (int*)alloc(128 * 4);
    int*   esrc   = (int*)alloc((size_t)E * 4);          // dst-sorted src ids
    float* dinv   = (float*)alloc((size_t)N * 4);
    uint*  hb     = (uint*)alloc((size_t)N * 32 * 4);    // h'  bf16 [N][64]
    float* o1     = (float*)alloc((size_t)N * NHID * 4); // f32 [N][64]
    uint*  h2b    = (uint*)alloc((size_t)N * 12 * 4);    // h2' bf16 [N][24]

    const int B = 256;
    int nb = (N + 1023) / 1024;

    hipMemsetAsync(cnt, 0, (size_t)N * 4, stream);
    k_count  <<<(E + B - 1) / B, B, 0, stream>>>(dst, cnt, E);
    k_scan1  <<<nb, 256, 0, stream>>>(cnt, rowptr, bsum, dinv, N);
    k_scan2  <<<1, 128, 0, stream>>>(bsum, nb);
    k_scan3  <<<nb, 256, 0, stream>>>(rowptr, fill, bsum, N, E);
    k_scatter<<<(E + B - 1) / B, B, 0, stream>>>(src, dst, fill, esrc, E);

    k_gemm1  <<<(N + 63) / 64, 256, 0, stream>>>(x, W1, dinv, hb, N);
    k_agg1   <<<(N + 3) / 4, 256, 0, stream>>>(rowptr, esrc, hb, dinv, b1, o1, N);
    k_gemm2  <<<(N + 127) / 128, 128, 0, stream>>>(o1, W2, dinv, h2b, N);
    k_agg2   <<<(N + 63) / 64, 256, 0, stream>>>(rowptr, esrc, h2b, dinv, b2, out, N);
}